// Round 20
// baseline (3723.169 us; speedup 1.0000x reference)
//
#include <hip/hip_runtime.h>
#include <hip/hip_bf16.h>

#define SEQ   512
#define BATCH 128
#define VOCAB 30000
#define EDIM  256
#define HDIM  256
#define NT    9

// ---------------- K0b: detect mask storage dtype ----------------
__global__ void k_detect(const unsigned char* __restrict__ m, int* __restrict__ flag) {
    __shared__ int ok_sh;
    if (threadIdx.x == 0) ok_sh = 1;
    __syncthreads();
    int b = threadIdx.x;  // 128 threads, one row each
    const uint4* row = (const uint4*)(m + b * SEQ);
    int ok = 1, prev = 1;
    for (int i = 0; i < SEQ / 16; ++i) {
        uint4 v = row[i];
        unsigned w[4] = {v.x, v.y, v.z, v.w};
        #pragma unroll
        for (int wi = 0; wi < 4; ++wi) {
            #pragma unroll
            for (int j = 0; j < 4; ++j) {
                int byte = (w[wi] >> (8 * j)) & 255;
                if (byte > 1 || byte > prev) ok = 0;
                prev = byte;
            }
        }
    }
    if (!ok) atomicAnd(&ok_sh, 0);
    __syncthreads();
    if (threadIdx.x == 0) *flag = ok_sh;
}

// ---------------- K1: table[v][n] = embed[v] . Wcat[n] + bias[n] ----------------
// r19-proven staging slot remap: 16 consecutive lanes write consecutive
// columns of one As/Bs row (2-way bank aliasing, free).
__global__ __launch_bounds__(256) void k_table_gemm(
    const float* __restrict__ emb, const float* __restrict__ Wf,
    const float* __restrict__ Wb, const float* __restrict__ bf,
    const float* __restrict__ bb, float* __restrict__ table) {
    __shared__ __align__(16) float As[64][68];  // [k][m]
    __shared__ __align__(16) float Bs[64][68];  // [k][n]
    int t  = threadIdx.x;
    int tx = t & 15, ty = t >> 4;
    int n0 = blockIdx.x * 64;
    int v0 = blockIdx.y * 64;
    float acc[4][4] = {};
    for (int kc = 0; kc < 4; ++kc) {
        #pragma unroll
        for (int rr = 0; rr < 4; ++rr) {
            int slot = t + rr * 256;
            int m  = (slot & 15) | ((slot >> 8) << 4);
            int kq = (slot >> 4) & 15;
            int v = v0 + m;
            float4 a = (v < VOCAB)
                ? *(const float4*)&emb[v * EDIM + kc * 64 + kq * 4]
                : make_float4(0.f, 0.f, 0.f, 0.f);
            As[kq * 4 + 0][m] = a.x; As[kq * 4 + 1][m] = a.y;
            As[kq * 4 + 2][m] = a.z; As[kq * 4 + 3][m] = a.w;
            int n = n0 + m;
            const float* Wrow = (n < 1024) ? &Wf[n * 256] : &Wb[(n - 1024) * 256];
            float4 bvec = *(const float4*)&Wrow[kc * 64 + kq * 4];
            Bs[kq * 4 + 0][m] = bvec.x; Bs[kq * 4 + 1][m] = bvec.y;
            Bs[kq * 4 + 2][m] = bvec.z; Bs[kq * 4 + 3][m] = bvec.w;
        }
        __syncthreads();
        #pragma unroll
        for (int k = 0; k < 64; ++k) {
            float4 a = *(const float4*)&As[k][ty * 4];
            float4 b = *(const float4*)&Bs[k][tx * 4];
            acc[0][0] += a.x * b.x; acc[0][1] += a.x * b.y; acc[0][2] += a.x * b.z; acc[0][3] += a.x * b.w;
            acc[1][0] += a.y * b.x; acc[1][1] += a.y * b.y; acc[1][2] += a.y * b.z; acc[1][3] += a.y * b.w;
            acc[2][0] += a.z * b.x; acc[2][1] += a.z * b.y; acc[2][2] += a.z * b.z; acc[2][3] += a.z * b.w;
            acc[3][0] += a.w * b.x; acc[3][1] += a.w * b.y; acc[3][2] += a.w * b.z; acc[3][3] += a.w * b.w;
        }
        __syncthreads();
    }
    int n = n0 + tx * 4;
    const float* bi = (n < 1024) ? &bf[n] : &bb[n - 1024];
    float4 bias = *(const float4*)bi;
    #pragma unroll
    for (int i = 0; i < 4; ++i) {
        int v = v0 + ty * 4 + i;
        if (v < VOCAB) {
            float4 o;
            o.x = acc[i][0] + bias.x; o.y = acc[i][1] + bias.y;
            o.z = acc[i][2] + bias.z; o.w = acc[i][3] + bias.w;
            *(float4*)&table[(size_t)v * 2048 + n] = o;
        }
    }
}

// ---------------- K2: clustered LSTM, 2 blocks/CU, full-reg W ----------------
// r20 = r16/r19 structure with two serial-chain cuts:
//  (a) DUAL-TAG publish: each nonlin wave's lane0 publishes its own half-chunk
//      tag right after its per-wave vmcnt(0) -- sh_ctr rendezvous deleted.
//      Pollers check both half-tags (same 64B line). Equality-poll replay
//      safety and 2-slot-ring skew argument unchanged.
//  (b) Emission on the copy-exempt wave (wv==myd, r17-validated mapping),
//      reading the r16-proven h_em stash -- copies start immediately.
// Everything else identical to r16: 512 blocks x 512 threads, 2 blocks/CU;
// cluster = bid>>3, myd = bid&7; dir = cluster&1, quad = cluster>>1;
// g = t>>4 owns rows 4g..4g+3; kc = t&15 owns k4 in {kc,kc+16,kc+32,kc+48};
// ALL W in 16 float4 regs; DPP butterfly; sh_g[4][132] pad; 2 barriers/step.
#define DPPXOR(dst, src, CTRL) { \
    int _i = __float_as_int(src); \
    int _r = __builtin_amdgcn_update_dpp(_i, _i, (CTRL), 0xF, 0xF, false); \
    dst = __int_as_float(_r); }

__global__ __attribute__((amdgpu_flat_work_group_size(512, 512), amdgpu_waves_per_eu(4, 4)))
void k_lstm_cl(
    const int* __restrict__ ids, const float* __restrict__ Whhf,
    const float* __restrict__ Whhb, const float* __restrict__ table,
    const float* __restrict__ Wout, float* __restrict__ emp,
    float* hx, int* tagbuf) {
    __shared__ float h_cur[4][256];            // 4 KB linear
    __shared__ float h_em[256];                // 1 KB stash (emitted batch)
    __shared__ float sh_g[4][132];             // gates [batch][gate*32+dim], pad
    __shared__ float wout_s[NT][257];

    const int t   = threadIdx.x;
    const int bid = blockIdx.x;
    const int cluster = bid >> 3;              // 0..63
    const int myd = bid & 7;                   // dim chunk
    const int dir = cluster & 1;
    const int quad = cluster >> 1;             // 0..31
    const int gbatch = quad * 4 + myd;         // emitted batch (if myd<4)

    const int lane = t & 63;
    const int wv   = t >> 6;                   // 0..7
    const int g    = t >> 4;                   // row-group 0..31
    const int kc   = t & 15;                   // k lane 0..15

    const int nb = (t >> 5) & 3;               // nonlin batch (t<128)
    const int nd = t & 31;                     // nonlin dim-in-chunk

    const float* Whh = dir ? Whhb : Whhf;

    for (int idx = t; idx < NT * 256; idx += 512)
        wout_s[idx >> 8][idx & 255] = Wout[(idx >> 8) * 512 + dir * 256 + (idx & 255)];
    for (int idx = t; idx < 1024; idx += 512)
        h_cur[idx >> 8][idx & 255] = 0.f;
    float c_state = 0.f;

    // FULL register-resident W: rows 4g..4g+3, 4 float4 chunks each (64 VGPR)
    float4 w0_0, w0_1, w0_2, w0_3, w1_0, w1_1, w1_2, w1_3;
    float4 w2_0, w2_1, w2_2, w2_3, w3_0, w3_1, w3_2, w3_3;
    {
        int lr0 = 4 * g, lr1 = 4 * g + 1, lr2 = 4 * g + 2, lr3 = 4 * g + 3;
        int gr0 = (lr0 >> 5) * 256 + myd * 32 + (lr0 & 31);
        int gr1 = (lr1 >> 5) * 256 + myd * 32 + (lr1 & 31);
        int gr2 = (lr2 >> 5) * 256 + myd * 32 + (lr2 & 31);
        int gr3 = (lr3 >> 5) * 256 + myd * 32 + (lr3 & 31);
        const float4* wp0 = (const float4*)(Whh + (size_t)gr0 * 256);
        const float4* wp1 = (const float4*)(Whh + (size_t)gr1 * 256);
        const float4* wp2 = (const float4*)(Whh + (size_t)gr2 * 256);
        const float4* wp3 = (const float4*)(Whh + (size_t)gr3 * 256);
        w0_0 = wp0[kc]; w0_1 = wp0[kc + 16]; w0_2 = wp0[kc + 32]; w0_3 = wp0[kc + 48];
        w1_0 = wp1[kc]; w1_1 = wp1[kc + 16]; w1_2 = wp1[kc + 32]; w1_3 = wp1[kc + 48];
        w2_0 = wp2[kc]; w2_1 = wp2[kc + 16]; w2_2 = wp2[kc + 32]; w2_3 = wp2[kc + 48];
        w3_0 = wp3[kc]; w3_1 = wp3[kc + 16]; w3_2 = wp3[kc + 32]; w3_3 = wp3[kc + 48];
    }
    __syncthreads();

    // xg prefetch for it=0 (nonlin threads t<128 hold i,f,g,o in regs)
    float xi = 0.f, xf = 0.f, xq = 0.f, xo = 0.f;
    if (t < 128) {
        int s0 = dir ? SEQ - 1 : 0;
        int id = ids[(quad * 4 + nb) * SEQ + s0];
        const float* tb = table + (size_t)id * 2048 + dir * 1024;
        int base = myd * 32 + nd;
        xi = tb[base]; xf = tb[256 + base]; xq = tb[512 + base]; xo = tb[768 + base];
    }

    #pragma unroll 1
    for (int it = 0; it < SEQ; ++it) {
        // stash emitted batch's h_{it-1} + dot
        if (myd < 4 && t < 256) h_em[t] = h_cur[myd][t];

        float a[16];
        #pragma unroll
        for (int m = 0; m < 16; ++m) a[m] = 0.f;

        #define DOTJ(J, W0, W1, W2, W3) { \
            const int off = 4 * (kc + 16 * (J)); \
            _Pragma("unroll") \
            for (int b = 0; b < 4; ++b) { \
                float4 hv = *(const float4*)(&h_cur[b][0] + off); \
                a[b]      += W0.x*hv.x + W0.y*hv.y + W0.z*hv.z + W0.w*hv.w; \
                a[4 + b]  += W1.x*hv.x + W1.y*hv.y + W1.z*hv.z + W1.w*hv.w; \
                a[8 + b]  += W2.x*hv.x + W2.y*hv.y + W2.z*hv.z + W2.w*hv.w; \
                a[12 + b] += W3.x*hv.x + W3.y*hv.y + W3.z*hv.z + W3.w*hv.w; } }
        DOTJ(0, w0_0, w1_0, w2_0, w3_0)
        DOTJ(1, w0_1, w1_1, w2_1, w3_1)
        DOTJ(2, w0_2, w1_2, w2_2, w3_2)
        DOTJ(3, w0_3, w1_3, w2_3, w3_3)
        #undef DOTJ

        // 4-stage thinning butterfly over 16 kc-lanes.
        #pragma unroll
        for (int m = 0; m < 8; ++m) {           // stride 1: quad_perm [1,0,3,2]
            int bit = kc & 1;
            float sent = bit ? a[m] : a[m + 8];
            float recv; DPPXOR(recv, sent, 0xB1)
            a[m] = (bit ? a[m + 8] : a[m]) + recv;
        }
        #pragma unroll
        for (int m = 0; m < 4; ++m) {           // stride 2: quad_perm [2,3,0,1]
            int bit = kc & 2;
            float sent = bit ? a[m] : a[m + 4];
            float recv; DPPXOR(recv, sent, 0x4E)
            a[m] = (bit ? a[m + 4] : a[m]) + recv;
        }
        #pragma unroll
        for (int m = 0; m < 2; ++m) {           // stride 4: ds shuffle
            int bit = kc & 4;
            float sent = bit ? a[m] : a[m + 2];
            float recv = __shfl_xor(sent, 4);
            a[m] = (bit ? a[m + 2] : a[m]) + recv;
        }
        {                                       // stride 8: row_ror:8
            int bit = kc & 8;
            float sent = bit ? a[0] : a[1];
            float recv; DPPXOR(recv, sent, 0x128)
            a[0] = (bit ? a[1] : a[0]) + recv;
        }
        {
            // lane kc holds tile = bitrev4(kc): r = tile>>2, b = tile&3
            int tile = ((kc & 1) << 3) | ((kc & 2) << 1) | ((kc & 4) >> 1) | ((kc & 8) >> 3);
            sh_g[tile & 3][4 * g + (tile >> 2)] = a[0];
        }
        __syncthreads();   // BARRIER A: gates ready, h_cur reads done, h_em ready

        const int p = it & 1;
        float* hxp = hx + (size_t)p * 65536 + (size_t)cluster * 1024;
        int* tags = tagbuf + p * 1024 + cluster * 16;

        if (t < 128) {
            // nonlin + publish (waves 0-1); dual-tag, no rendezvous
            float iv = sh_g[nb][nd]      + xi;
            float fv = sh_g[nb][32 + nd] + xf;
            float gv = sh_g[nb][64 + nd] + xq;
            float ov = sh_g[nb][96 + nd] + xo;
            float si = 1.f / (1.f + expf(-iv));
            float sf = 1.f / (1.f + expf(-fv));
            float so = 1.f / (1.f + expf(-ov));
            float tg = tanhf(gv);
            c_state = sf * c_state + si * tg;
            float hh = so * tanhf(c_state);
            int dl = myd * 32 + nd;
            h_cur[nb][dl] = hh;
            __hip_atomic_store(&hxp[nb * 256 + dl], hh,
                               __ATOMIC_RELAXED, __HIP_MEMORY_SCOPE_AGENT);
            asm volatile("s_waitcnt vmcnt(0)" ::: "memory");
            if (lane == 0)
                __hip_atomic_store(&tags[myd * 2 + wv], it,
                                   __ATOMIC_RELAXED, __HIP_MEMORY_SCOPE_AGENT);
            // xg prefetch for it+1 (completes during next dot)
            if (it < SEQ - 1) {
                int sn = dir ? (SEQ - 2 - it) : (it + 1);
                int id = ids[(quad * 4 + nb) * SEQ + sn];
                const float* tb = table + (size_t)id * 2048 + dir * 1024;
                int base = myd * 32 + nd;
                xi = tb[base]; xf = tb[256 + base]; xq = tb[512 + base]; xo = tb[768 + base];
            }
        }

        if (wv != myd) {
            // copy duty: poll both half-tags of chunk wv, then copy it
            while (__hip_atomic_load(&tags[wv * 2 + 0], __ATOMIC_RELAXED,
                                     __HIP_MEMORY_SCOPE_AGENT) != it ||
                   __hip_atomic_load(&tags[wv * 2 + 1], __ATOMIC_RELAXED,
                                     __HIP_MEMORY_SCOPE_AGENT) != it)
                __builtin_amdgcn_s_sleep(1);
            #pragma unroll
            for (int rep = 0; rep < 2; ++rep) {
                int idx = rep * 64 + lane;
                int b2 = idx >> 5, nd2 = idx & 31;
                float vv = __hip_atomic_load(&hxp[b2 * 256 + wv * 32 + nd2],
                                             __ATOMIC_RELAXED, __HIP_MEMORY_SCOPE_AGENT);
                h_cur[b2][wv * 32 + nd2] = vv;
            }
        } else if (myd < 4 && it > 0) {
            // emission of h_{it-1} from h_em on the copy-exempt wave
            int sp = dir ? (SEQ - it) : (it - 1);
            int eg = lane >> 3, ee = lane & 7;
            float pe = 0.f;
            #pragma unroll
            for (int j = 0; j < 8; ++j) {
                float4 h4 = *(const float4*)(&h_em[ee * 32 + j * 4]);
                float4 w4 = *(const float4*)(&wout_s[eg][ee * 32 + j * 4]);
                pe += h4.x*w4.x + h4.y*w4.y + h4.z*w4.z + h4.w*w4.w;
            }
            pe += __shfl_xor(pe, 1); pe += __shfl_xor(pe, 2); pe += __shfl_xor(pe, 4);
            if (ee == 0)
                emp[(((size_t)(dir * BATCH) + gbatch) * SEQ + sp) * NT + eg] = pe;
            if (eg == 0) {  // tag 8 second pass (lanes 0..7)
                float p8 = 0.f;
                #pragma unroll
                for (int j = 0; j < 8; ++j) {
                    float4 h4 = *(const float4*)(&h_em[ee * 32 + j * 4]);
                    float4 w4 = *(const float4*)(&wout_s[8][ee * 32 + j * 4]);
                    p8 += h4.x*w4.x + h4.y*w4.y + h4.z*w4.z + h4.w*w4.w;
                }
                p8 += __shfl_xor(p8, 1); p8 += __shfl_xor(p8, 2); p8 += __shfl_xor(p8, 4);
                if (ee == 0)
                    emp[(((size_t)(dir * BATCH) + gbatch) * SEQ + sp) * NT + 8] = p8;
            }
        }
        __syncthreads();   // BARRIER B: h_cur = full h_it
    }

    // final emission for h_{511}
    if (myd < 4 && t < 256) h_em[t] = h_cur[myd][t];
    __syncthreads();
    if (myd < 4 && t < 144) {
        int etg2 = t >> 4, el2 = t & 15;
        int sp = dir ? 0 : (SEQ - 1);
        float pe = 0.f;
        #pragma unroll
        for (int j = 0; j < 16; ++j)
            pe += wout_s[etg2][el2 + 16 * j] * h_em[el2 + 16 * j];
        pe += __shfl_xor(pe, 1); pe += __shfl_xor(pe, 2);
        pe += __shfl_xor(pe, 4); pe += __shfl_xor(pe, 8);
        if (el2 == 0)
            emp[(((size_t)(dir * BATCH) + gbatch) * SEQ + sp) * NT + etg2] = pe;
    }
}

// ---------------- K3: Viterbi decode per batch ----------------
__global__ __launch_bounds__(64) void k_viterbi(
    const float* __restrict__ emp, const float* __restrict__ b_out,
    const float* __restrict__ start_t, const float* __restrict__ end_t,
    const float* __restrict__ trans, const void* __restrict__ maskp,
    const int* __restrict__ mask_is_bool, int* __restrict__ out) {
    __shared__ float sh_em[SEQ][NT];
    __shared__ float sh_score[NT];
    __shared__ float sh_trans[NT * NT];
    __shared__ unsigned char sh_mask[SEQ];
    __shared__ unsigned char sh_hist[SEQ - 1][NT];
    __shared__ unsigned char sh_tags[SEQ];
    int b = blockIdx.x;
    int t = threadIdx.x;
    int isb = *mask_is_bool;
    for (int idx = t; idx < SEQ * NT; idx += 64) {
        int s = idx / NT, tg = idx % NT;
        sh_em[s][tg] = emp[((size_t)b * SEQ + s) * NT + tg]
                     + emp[(((size_t)BATCH + b) * SEQ + s) * NT + tg]
                     + b_out[tg];
    }
    if (isb) {
        const unsigned char* m8 = (const unsigned char*)maskp;
        for (int idx = t; idx < SEQ; idx += 64) sh_mask[idx] = m8[b * SEQ + idx];
    } else {
        const int* m32 = (const int*)maskp;
        for (int idx = t; idx < SEQ; idx += 64) sh_mask[idx] = (unsigned char)(m32[b * SEQ + idx] != 0);
    }
    for (int idx = t; idx < NT * NT; idx += 64) sh_trans[idx] = trans[idx];
    __syncthreads();
    float sc = 0.f;
    if (t < NT) { sc = start_t[t] + sh_em[0][t]; sh_score[t] = sc; }
    __syncthreads();
    for (int s = 1; s < SEQ; ++s) {
        if (t < NT) {
            float m = -3.4e38f; int bp = 0;
            #pragma unroll
            for (int i = 0; i < NT; ++i) {
                float v = sh_score[i] + sh_trans[i * NT + t];
                if (v > m) { m = v; bp = i; }
            }
            sh_hist[s - 1][t] = (unsigned char)bp;
            float best = m + sh_em[s][t];
            if (sh_mask[s]) sc = best;
        }
        __syncthreads();
        if (t < NT) sh_score[t] = sc;
        __syncthreads();
    }
    if (t == 0) {
        float bb = -3.4e38f; int tag = 0;
        for (int j = 0; j < NT; ++j) {
            float v = sh_score[j] + end_t[j];
            if (v > bb) { bb = v; tag = j; }
        }
        for (int pos = SEQ - 1; pos >= 1; --pos) {
            sh_tags[pos] = (unsigned char)tag;
            if (sh_mask[pos]) tag = sh_hist[pos - 1][tag];
        }
        sh_tags[0] = (unsigned char)tag;
    }
    __syncthreads();
    for (int idx = t; idx < SEQ; idx += 64) {
        out[b * SEQ + idx] = sh_mask[idx] ? (int)sh_tags[idx] : 0;
    }
}

extern "C" void kernel_launch(void* const* d_in, const int* in_sizes, int n_in,
                              void* d_out, int out_size, void* d_ws, size_t ws_size,
                              hipStream_t stream) {
    const int*   ids  = (const int*)d_in[0];
    const void*  mask = d_in[1];
    const float* emb  = (const float*)d_in[2];
    const float* Wihf = (const float*)d_in[3];
    const float* Whhf = (const float*)d_in[4];
    const float* bfv  = (const float*)d_in[5];
    const float* Wihb = (const float*)d_in[6];
    const float* Whhb = (const float*)d_in[7];
    const float* bbv  = (const float*)d_in[8];
    const float* Wout = (const float*)d_in[9];
    const float* bout = (const float*)d_in[10];
    const float* st   = (const float*)d_in[11];
    const float* en   = (const float*)d_in[12];
    const float* tr   = (const float*)d_in[13];
    int* out = (int*)d_out;

    char* ws = (char*)d_ws;
    float* table = (float*)ws;                                       // 245,760,000 B
    float* emp   = (float*)(ws + 245760000);                         //   4,718,592 B
    float* hx    = (float*)(ws + 245760000 + 4718592);               //     524,288 B
    int*   tags  = (int*)(ws + 245760000 + 4718592 + 524288);        //       8,192 B
    int*   flag  = (int*)(ws + 245760000 + 4718592 + 524288 + 8192); //           4 B

    k_detect<<<1, 128, 0, stream>>>((const unsigned char*)mask, flag);
    dim3 g1(32, 469);
    k_table_gemm<<<g1, 256, 0, stream>>>(emb, Wihf, Wihb, bfv, bbv, table);
    k_lstm_cl<<<512, 512, 0, stream>>>(ids, Whhf, Whhb, table, Wout, emp, hx, tags);
    k_viterbi<<<128, 64, 0, stream>>>(emp, bout, st, en, tr, mask, flag, out);
}

// Round 21
// 3371.524 us; speedup vs baseline: 1.1043x; 1.1043x over previous
//
#include <hip/hip_runtime.h>
#include <hip/hip_bf16.h>

#define SEQ   512
#define BATCH 128
#define VOCAB 30000
#define EDIM  256
#define HDIM  256
#define NT    9

// ---------------- K0b: detect mask storage dtype ----------------
__global__ void k_detect(const unsigned char* __restrict__ m, int* __restrict__ flag) {
    __shared__ int ok_sh;
    if (threadIdx.x == 0) ok_sh = 1;
    __syncthreads();
    int b = threadIdx.x;  // 128 threads, one row each
    const uint4* row = (const uint4*)(m + b * SEQ);
    int ok = 1, prev = 1;
    for (int i = 0; i < SEQ / 16; ++i) {
        uint4 v = row[i];
        unsigned w[4] = {v.x, v.y, v.z, v.w};
        #pragma unroll
        for (int wi = 0; wi < 4; ++wi) {
            #pragma unroll
            for (int j = 0; j < 4; ++j) {
                int byte = (w[wi] >> (8 * j)) & 255;
                if (byte > 1 || byte > prev) ok = 0;
                prev = byte;
            }
        }
    }
    if (!ok) atomicAnd(&ok_sh, 0);
    __syncthreads();
    if (threadIdx.x == 0) *flag = ok_sh;
}

// ---------------- K1: table[v][n] = embed[v] . Wcat[n] + bias[n] ----------------
// r19-proven staging slot remap: 16 consecutive lanes write consecutive
// columns of one As/Bs row (2-way bank aliasing, free).
__global__ __launch_bounds__(256) void k_table_gemm(
    const float* __restrict__ emb, const float* __restrict__ Wf,
    const float* __restrict__ Wb, const float* __restrict__ bf,
    const float* __restrict__ bb, float* __restrict__ table) {
    __shared__ __align__(16) float As[64][68];  // [k][m]
    __shared__ __align__(16) float Bs[64][68];  // [k][n]
    int t  = threadIdx.x;
    int tx = t & 15, ty = t >> 4;
    int n0 = blockIdx.x * 64;
    int v0 = blockIdx.y * 64;
    float acc[4][4] = {};
    for (int kc = 0; kc < 4; ++kc) {
        #pragma unroll
        for (int rr = 0; rr < 4; ++rr) {
            int slot = t + rr * 256;
            int m  = (slot & 15) | ((slot >> 8) << 4);
            int kq = (slot >> 4) & 15;
            int v = v0 + m;
            float4 a = (v < VOCAB)
                ? *(const float4*)&emb[v * EDIM + kc * 64 + kq * 4]
                : make_float4(0.f, 0.f, 0.f, 0.f);
            As[kq * 4 + 0][m] = a.x; As[kq * 4 + 1][m] = a.y;
            As[kq * 4 + 2][m] = a.z; As[kq * 4 + 3][m] = a.w;
            int n = n0 + m;
            const float* Wrow = (n < 1024) ? &Wf[n * 256] : &Wb[(n - 1024) * 256];
            float4 bvec = *(const float4*)&Wrow[kc * 64 + kq * 4];
            Bs[kq * 4 + 0][m] = bvec.x; Bs[kq * 4 + 1][m] = bvec.y;
            Bs[kq * 4 + 2][m] = bvec.z; Bs[kq * 4 + 3][m] = bvec.w;
        }
        __syncthreads();
        #pragma unroll
        for (int k = 0; k < 64; ++k) {
            float4 a = *(const float4*)&As[k][ty * 4];
            float4 b = *(const float4*)&Bs[k][tx * 4];
            acc[0][0] += a.x * b.x; acc[0][1] += a.x * b.y; acc[0][2] += a.x * b.z; acc[0][3] += a.x * b.w;
            acc[1][0] += a.y * b.x; acc[1][1] += a.y * b.y; acc[1][2] += a.y * b.z; acc[1][3] += a.y * b.w;
            acc[2][0] += a.z * b.x; acc[2][1] += a.z * b.y; acc[2][2] += a.z * b.z; acc[2][3] += a.z * b.w;
            acc[3][0] += a.w * b.x; acc[3][1] += a.w * b.y; acc[3][2] += a.w * b.z; acc[3][3] += a.w * b.w;
        }
        __syncthreads();
    }
    int n = n0 + tx * 4;
    const float* bi = (n < 1024) ? &bf[n] : &bb[n - 1024];
    float4 bias = *(const float4*)bi;
    #pragma unroll
    for (int i = 0; i < 4; ++i) {
        int v = v0 + ty * 4 + i;
        if (v < VOCAB) {
            float4 o;
            o.x = acc[i][0] + bias.x; o.y = acc[i][1] + bias.y;
            o.z = acc[i][2] + bias.z; o.w = acc[i][3] + bias.w;
            *(float4*)&table[(size_t)v * 2048 + n] = o;
        }
    }
}

// ---------------- K2: clustered LSTM, 2 blocks/CU, full-reg W ----------------
// FINAL = r16/r19 structure (best measured). Structural experiments r13
// (fused nonlin), r17/r18 (spin dataflow), r20 (dual-tag + emission remap)
// all regressed vs this two-barrier shape; the exchange chain is latency-
// floor (L3 is the only coherent point for cross-CU h-exchange, G16).
// 512 blocks x 512 threads, 2 blocks/CU (16 waves/CU). cluster = bid>>3 (64),
// myd = bid&7. dir = cluster&1, quad = cluster>>1: batches quad*4..+3.
// g = t>>4 owns rows 4g..4g+3; kc = t&15 owns k4 in {kc,kc+16,kc+32,kc+48};
// ALL W in 16 float4 regs. DPP butterfly (strides 1,2,8) + shfl (stride 4);
// lane kc ends with tile bitrev4(kc). sh_g[4][132] pad. Exchange: relaxed
// agent atomics -> L3, per-wave vmcnt(0), LDS ctr (2 nonlin waves) -> t0
// publishes monotonic tag, 2-slot ring; wave wv polls+copies peer wv.
// Emission: blocks myd<4 emit batch quad*4+myd from h_em stash.
#define DPPXOR(dst, src, CTRL) { \
    int _i = __float_as_int(src); \
    int _r = __builtin_amdgcn_update_dpp(_i, _i, (CTRL), 0xF, 0xF, false); \
    dst = __int_as_float(_r); }

__global__ __attribute__((amdgpu_flat_work_group_size(512, 512), amdgpu_waves_per_eu(4, 4)))
void k_lstm_cl(
    const int* __restrict__ ids, const float* __restrict__ Whhf,
    const float* __restrict__ Whhb, const float* __restrict__ table,
    const float* __restrict__ Wout, float* __restrict__ emp,
    float* hx, int* tagbuf) {
    __shared__ float h_cur[4][256];            // 4 KB linear
    __shared__ float h_em[256];                // 1 KB stash (emitted batch)
    __shared__ float sh_g[4][132];             // gates [batch][gate*32+dim], pad
    __shared__ float wout_s[NT][257];
    __shared__ int   sh_ctr;

    const int t   = threadIdx.x;
    const int bid = blockIdx.x;
    const int cluster = bid >> 3;              // 0..63
    const int myd = bid & 7;                   // dim chunk
    const int dir = cluster & 1;
    const int quad = cluster >> 1;             // 0..31
    const int gbatch = quad * 4 + myd;         // emitted batch (if myd<4)

    const int lane = t & 63;
    const int wv   = t >> 6;                   // 0..7
    const int g    = t >> 4;                   // row-group 0..31
    const int kc   = t & 15;                   // k lane 0..15

    const int nb = (t >> 5) & 3;               // nonlin batch (t<128)
    const int nd = t & 31;                     // nonlin dim-in-chunk

    const int em = t - 256;                    // emission map (256<=t<400)
    const int etg = em >> 4, el = em & 15;

    const float* Whh = dir ? Whhb : Whhf;

    if (t == 0) sh_ctr = 0;
    for (int idx = t; idx < NT * 256; idx += 512)
        wout_s[idx >> 8][idx & 255] = Wout[(idx >> 8) * 512 + dir * 256 + (idx & 255)];
    for (int idx = t; idx < 1024; idx += 512)
        h_cur[idx >> 8][idx & 255] = 0.f;
    float c_state = 0.f;

    // FULL register-resident W: rows 4g..4g+3, 4 float4 chunks each (64 VGPR)
    float4 w0_0, w0_1, w0_2, w0_3, w1_0, w1_1, w1_2, w1_3;
    float4 w2_0, w2_1, w2_2, w2_3, w3_0, w3_1, w3_2, w3_3;
    {
        int lr0 = 4 * g, lr1 = 4 * g + 1, lr2 = 4 * g + 2, lr3 = 4 * g + 3;
        int gr0 = (lr0 >> 5) * 256 + myd * 32 + (lr0 & 31);
        int gr1 = (lr1 >> 5) * 256 + myd * 32 + (lr1 & 31);
        int gr2 = (lr2 >> 5) * 256 + myd * 32 + (lr2 & 31);
        int gr3 = (lr3 >> 5) * 256 + myd * 32 + (lr3 & 31);
        const float4* wp0 = (const float4*)(Whh + (size_t)gr0 * 256);
        const float4* wp1 = (const float4*)(Whh + (size_t)gr1 * 256);
        const float4* wp2 = (const float4*)(Whh + (size_t)gr2 * 256);
        const float4* wp3 = (const float4*)(Whh + (size_t)gr3 * 256);
        w0_0 = wp0[kc]; w0_1 = wp0[kc + 16]; w0_2 = wp0[kc + 32]; w0_3 = wp0[kc + 48];
        w1_0 = wp1[kc]; w1_1 = wp1[kc + 16]; w1_2 = wp1[kc + 32]; w1_3 = wp1[kc + 48];
        w2_0 = wp2[kc]; w2_1 = wp2[kc + 16]; w2_2 = wp2[kc + 32]; w2_3 = wp2[kc + 48];
        w3_0 = wp3[kc]; w3_1 = wp3[kc + 16]; w3_2 = wp3[kc + 32]; w3_3 = wp3[kc + 48];
    }
    __syncthreads();

    // xg prefetch for it=0 (nonlin threads t<128 hold i,f,g,o in regs)
    float xi = 0.f, xf = 0.f, xq = 0.f, xo = 0.f;
    if (t < 128) {
        int s0 = dir ? SEQ - 1 : 0;
        int id = ids[(quad * 4 + nb) * SEQ + s0];
        const float* tb = table + (size_t)id * 2048 + dir * 1024;
        int base = myd * 32 + nd;
        xi = tb[base]; xf = tb[256 + base]; xq = tb[512 + base]; xo = tb[768 + base];
    }

    #pragma unroll 1
    for (int it = 0; it < SEQ; ++it) {
        // stash emitted batch's h_{it-1} + dot
        if (myd < 4 && t < 256) h_em[t] = h_cur[myd][t];

        float a[16];
        #pragma unroll
        for (int m = 0; m < 16; ++m) a[m] = 0.f;

        #define DOTJ(J, W0, W1, W2, W3) { \
            const int off = 4 * (kc + 16 * (J)); \
            _Pragma("unroll") \
            for (int b = 0; b < 4; ++b) { \
                float4 hv = *(const float4*)(&h_cur[b][0] + off); \
                a[b]      += W0.x*hv.x + W0.y*hv.y + W0.z*hv.z + W0.w*hv.w; \
                a[4 + b]  += W1.x*hv.x + W1.y*hv.y + W1.z*hv.z + W1.w*hv.w; \
                a[8 + b]  += W2.x*hv.x + W2.y*hv.y + W2.z*hv.z + W2.w*hv.w; \
                a[12 + b] += W3.x*hv.x + W3.y*hv.y + W3.z*hv.z + W3.w*hv.w; } }
        DOTJ(0, w0_0, w1_0, w2_0, w3_0)
        DOTJ(1, w0_1, w1_1, w2_1, w3_1)
        DOTJ(2, w0_2, w1_2, w2_2, w3_2)
        DOTJ(3, w0_3, w1_3, w2_3, w3_3)
        #undef DOTJ

        // 4-stage thinning butterfly over 16 kc-lanes.
        #pragma unroll
        for (int m = 0; m < 8; ++m) {           // stride 1: quad_perm [1,0,3,2]
            int bit = kc & 1;
            float sent = bit ? a[m] : a[m + 8];
            float recv; DPPXOR(recv, sent, 0xB1)
            a[m] = (bit ? a[m + 8] : a[m]) + recv;
        }
        #pragma unroll
        for (int m = 0; m < 4; ++m) {           // stride 2: quad_perm [2,3,0,1]
            int bit = kc & 2;
            float sent = bit ? a[m] : a[m + 4];
            float recv; DPPXOR(recv, sent, 0x4E)
            a[m] = (bit ? a[m + 4] : a[m]) + recv;
        }
        #pragma unroll
        for (int m = 0; m < 2; ++m) {           // stride 4: ds shuffle
            int bit = kc & 4;
            float sent = bit ? a[m] : a[m + 2];
            float recv = __shfl_xor(sent, 4);
            a[m] = (bit ? a[m + 2] : a[m]) + recv;
        }
        {                                       // stride 8: row_ror:8
            int bit = kc & 8;
            float sent = bit ? a[0] : a[1];
            float recv; DPPXOR(recv, sent, 0x128)
            a[0] = (bit ? a[1] : a[0]) + recv;
        }
        {
            // lane kc holds tile = bitrev4(kc): r = tile>>2, b = tile&3
            int tile = ((kc & 1) << 3) | ((kc & 2) << 1) | ((kc & 4) >> 1) | ((kc & 8) >> 3);
            sh_g[tile & 3][4 * g + (tile >> 2)] = a[0];
        }
        __syncthreads();   // BARRIER A: gates ready, h_cur reads done, h_em ready

        const int p = it & 1;
        float* hxp = hx + (size_t)p * 65536 + (size_t)cluster * 1024;
        int* tags = tagbuf + p * 512 + cluster * 8;

        if (t < 128) {
            // nonlin + publish (waves 0-1)
            float iv = sh_g[nb][nd]      + xi;
            float fv = sh_g[nb][32 + nd] + xf;
            float gv = sh_g[nb][64 + nd] + xq;
            float ov = sh_g[nb][96 + nd] + xo;
            float si = 1.f / (1.f + expf(-iv));
            float sf = 1.f / (1.f + expf(-fv));
            float so = 1.f / (1.f + expf(-ov));
            float tg = tanhf(gv);
            c_state = sf * c_state + si * tg;
            float hh = so * tanhf(c_state);
            int dl = myd * 32 + nd;
            h_cur[nb][dl] = hh;
            __hip_atomic_store(&hxp[nb * 256 + dl], hh,
                               __ATOMIC_RELAXED, __HIP_MEMORY_SCOPE_AGENT);
            asm volatile("s_waitcnt vmcnt(0)" ::: "memory");
            if (lane == 0) atomicAdd(&sh_ctr, 1);
            if (t == 0) {
                while (__hip_atomic_load(&sh_ctr, __ATOMIC_RELAXED,
                                         __HIP_MEMORY_SCOPE_WORKGROUP) < 2 * (it + 1)) {}
                __hip_atomic_store(&tags[myd], it,
                                   __ATOMIC_RELAXED, __HIP_MEMORY_SCOPE_AGENT);
            }
            // xg prefetch for it+1 (completes during next dot)
            if (it < SEQ - 1) {
                int sn = dir ? (SEQ - 2 - it) : (it + 1);
                int id = ids[(quad * 4 + nb) * SEQ + sn];
                const float* tb = table + (size_t)id * 2048 + dir * 1024;
                int base = myd * 32 + nd;
                xi = tb[base]; xf = tb[256 + base]; xq = tb[512 + base]; xo = tb[768 + base];
            }
        } else if (em >= 0 && em < 144 && myd < 4) {
            // emission for h_{it-1} from linear stash
            if (it > 0) {
                int sp = dir ? (SEQ - it) : (it - 1);
                float pe = 0.f;
                #pragma unroll
                for (int j = 0; j < 16; ++j)
                    pe += wout_s[etg][el + 16 * j] * h_em[el + 16 * j];
                pe += __shfl_xor(pe, 1); pe += __shfl_xor(pe, 2);
                pe += __shfl_xor(pe, 4); pe += __shfl_xor(pe, 8);
                if (el == 0)
                    emp[(((size_t)(dir * BATCH) + gbatch) * SEQ + sp) * NT + etg] = pe;
            }
        }

        // copy duty: wave wv polls + copies peer wv (skip own chunk)
        if (wv != myd) {
            while (__hip_atomic_load(&tags[wv], __ATOMIC_RELAXED,
                                     __HIP_MEMORY_SCOPE_AGENT) != it)
                __builtin_amdgcn_s_sleep(1);
            #pragma unroll
            for (int rep = 0; rep < 2; ++rep) {
                int idx = rep * 64 + lane;
                int b2 = idx >> 5, nd2 = idx & 31;
                float vv = __hip_atomic_load(&hxp[b2 * 256 + wv * 32 + nd2],
                                             __ATOMIC_RELAXED, __HIP_MEMORY_SCOPE_AGENT);
                h_cur[b2][wv * 32 + nd2] = vv;
            }
        }
        __syncthreads();   // BARRIER B: h_cur = full h_it
    }

    // final emission for h_{511}
    if (myd < 4 && t < 256) h_em[t] = h_cur[myd][t];
    __syncthreads();
    if (myd < 4 && t < 144) {
        int etg2 = t >> 4, el2 = t & 15;
        int sp = dir ? 0 : (SEQ - 1);
        float pe = 0.f;
        #pragma unroll
        for (int j = 0; j < 16; ++j)
            pe += wout_s[etg2][el2 + 16 * j] * h_em[el2 + 16 * j];
        pe += __shfl_xor(pe, 1); pe += __shfl_xor(pe, 2);
        pe += __shfl_xor(pe, 4); pe += __shfl_xor(pe, 8);
        if (el2 == 0)
            emp[(((size_t)(dir * BATCH) + gbatch) * SEQ + sp) * NT + etg2] = pe;
    }
}

// ---------------- K3: Viterbi decode per batch ----------------
__global__ __launch_bounds__(64) void k_viterbi(
    const float* __restrict__ emp, const float* __restrict__ b_out,
    const float* __restrict__ start_t, const float* __restrict__ end_t,
    const float* __restrict__ trans, const void* __restrict__ maskp,
    const int* __restrict__ mask_is_bool, int* __restrict__ out) {
    __shared__ float sh_em[SEQ][NT];
    __shared__ float sh_score[NT];
    __shared__ float sh_trans[NT * NT];
    __shared__ unsigned char sh_mask[SEQ];
    __shared__ unsigned char sh_hist[SEQ - 1][NT];
    __shared__ unsigned char sh_tags[SEQ];
    int b = blockIdx.x;
    int t = threadIdx.x;
    int isb = *mask_is_bool;
    for (int idx = t; idx < SEQ * NT; idx += 64) {
        int s = idx / NT, tg = idx % NT;
        sh_em[s][tg] = emp[((size_t)b * SEQ + s) * NT + tg]
                     + emp[(((size_t)BATCH + b) * SEQ + s) * NT + tg]
                     + b_out[tg];
    }
    if (isb) {
        const unsigned char* m8 = (const unsigned char*)maskp;
        for (int idx = t; idx < SEQ; idx += 64) sh_mask[idx] = m8[b * SEQ + idx];
    } else {
        const int* m32 = (const int*)maskp;
        for (int idx = t; idx < SEQ; idx += 64) sh_mask[idx] = (unsigned char)(m32[b * SEQ + idx] != 0);
    }
    for (int idx = t; idx < NT * NT; idx += 64) sh_trans[idx] = trans[idx];
    __syncthreads();
    float sc = 0.f;
    if (t < NT) { sc = start_t[t] + sh_em[0][t]; sh_score[t] = sc; }
    __syncthreads();
    for (int s = 1; s < SEQ; ++s) {
        if (t < NT) {
            float m = -3.4e38f; int bp = 0;
            #pragma unroll
            for (int i = 0; i < NT; ++i) {
                float v = sh_score[i] + sh_trans[i * NT + t];
                if (v > m) { m = v; bp = i; }
            }
            sh_hist[s - 1][t] = (unsigned char)bp;
            float best = m + sh_em[s][t];
            if (sh_mask[s]) sc = best;
        }
        __syncthreads();
        if (t < NT) sh_score[t] = sc;
        __syncthreads();
    }
    if (t == 0) {
        float bb = -3.4e38f; int tag = 0;
        for (int j = 0; j < NT; ++j) {
            float v = sh_score[j] + end_t[j];
            if (v > bb) { bb = v; tag = j; }
        }
        for (int pos = SEQ - 1; pos >= 1; --pos) {
            sh_tags[pos] = (unsigned char)tag;
            if (sh_mask[pos]) tag = sh_hist[pos - 1][tag];
        }
        sh_tags[0] = (unsigned char)tag;
    }
    __syncthreads();
    for (int idx = t; idx < SEQ; idx += 64) {
        out[b * SEQ + idx] = sh_mask[idx] ? (int)sh_tags[idx] : 0;
    }
}

extern "C" void kernel_launch(void* const* d_in, const int* in_sizes, int n_in,
                              void* d_out, int out_size, void* d_ws, size_t ws_size,
                              hipStream_t stream) {
    const int*   ids  = (const int*)d_in[0];
    const void*  mask = d_in[1];
    const float* emb  = (const float*)d_in[2];
    const float* Wihf = (const float*)d_in[3];
    const float* Whhf = (const float*)d_in[4];
    const float* bfv  = (const float*)d_in[5];
    const float* Wihb = (const float*)d_in[6];
    const float* Whhb = (const float*)d_in[7];
    const float* bbv  = (const float*)d_in[8];
    const float* Wout = (const float*)d_in[9];
    const float* bout = (const float*)d_in[10];
    const float* st   = (const float*)d_in[11];
    const float* en   = (const float*)d_in[12];
    const float* tr   = (const float*)d_in[13];
    int* out = (int*)d_out;

    char* ws = (char*)d_ws;
    float* table = (float*)ws;                                       // 245,760,000 B
    float* emp   = (float*)(ws + 245760000);                         //   4,718,592 B
    float* hx    = (float*)(ws + 245760000 + 4718592);               //     524,288 B
    int*   tags  = (int*)(ws + 245760000 + 4718592 + 524288);        //       4,096 B
    int*   flag  = (int*)(ws + 245760000 + 4718592 + 524288 + 4096); //           4 B

    k_detect<<<1, 128, 0, stream>>>((const unsigned char*)mask, flag);
    dim3 g1(32, 469);
    k_table_gemm<<<g1, 256, 0, stream>>>(emb, Wihf, Wihb, bfv, bbv, table);
    k_lstm_cl<<<512, 512, 0, stream>>>(ids, Whhf, Whhb, table, Wout, emp, hx, tags);
    k_viterbi<<<128, 64, 0, stream>>>(emp, bout, st, en, tr, mask, flag, out);
}